// Round 5
// baseline (766.670 us; speedup 1.0000x reference)
//
#include <hip/hip_runtime.h>
#include <math.h>

typedef __attribute__((ext_vector_type(8))) short bf8;
typedef __attribute__((ext_vector_type(4))) float f32x4;
typedef __attribute__((ext_vector_type(4))) unsigned short us4;

#define NTHR 1024

// ---- LDS layout (bytes). All "planes" are bf16, XOR-swizzled byte^=((row&7)<<4).
#define XHI 0u          // x hi   [64][256] bf16, row stride 512B
#define XLO 32768u      // x lo
#define GHI 65536u      // rh / scratch hi [64][128], row stride 256B
#define GLO 81920u
#define H1HI 98304u     // h1 hi [64][128]
#define H1LO 114688u
#define SHI 131072u     // h2 hi [64][128]
#define SLO 147456u
#define LDS_TOTAL 163840

// ---- workspace layout (bytes)
#define WS_LFRAG 0                      // 2 x 1KB L fragments (hi, lo)
#define WS_W1G   4096                   // 16nt*12ks*2*1024 = 393216
#define WS_W1C   (WS_W1G + 393216)      // 8nt*12ks*2*1024 = 196608
#define WS_W2G   (WS_W1C + 196608)      // 16nt*8ks*2*1024 = 262144
#define WS_W2C   (WS_W2G + 262144)      // 8nt*8ks*2*1024 = 131072

__device__ __forceinline__ unsigned short f2bf(float x) {
    unsigned u = __float_as_uint(x);
    unsigned r = (u + 0x7fffu + ((u >> 16) & 1u)) >> 16;
    return (unsigned short)r;
}
__device__ __forceinline__ float bf2f(unsigned short h) {
    return __uint_as_float(((unsigned)h) << 16);
}
__device__ __forceinline__ f32x4 mfma16(bf8 a, bf8 b, f32x4 c) {
    return __builtin_amdgcn_mfma_f32_16x16x32_bf16(a, b, c, 0, 0, 0);
}

// One nt-tile GEMM segment: 4 M-tiles, KS K-steps, split-bf16 (3 mfma per frag per ks).
// wp = weight frag base for (nt, ksBase) + l*16. B loaded ONCE per block (this wave only).
template<int KS>
__device__ __forceinline__ void gemmSeg(const char* sm, unsigned hiO, unsigned loO, unsigned rs,
                                        const char* wp, unsigned l, f32x4* acc) {
    const unsigned lrow = l & 15u, lk = l >> 4;
    const unsigned sw = (lrow & 7u) << 4;
#pragma unroll 2
    for (int ks = 0; ks < KS; ++ks) {
        const unsigned kb = ((unsigned)ks * 64u + lk * 16u) ^ sw;
        const bf8 bh = *(const bf8*)(wp + (size_t)ks * 2048u);
        const bf8 bl = *(const bf8*)(wp + (size_t)ks * 2048u + 1024u);
#pragma unroll
        for (int m = 0; m < 4; ++m) {
            const unsigned ro = ((unsigned)m * 16u + lrow) * rs;
            const bf8 ah = *(const bf8*)(sm + hiO + ro + kb);
            const bf8 al = *(const bf8*)(sm + loO + ro + kb);
            acc[m] = mfma16(al, bh, mfma16(ah, bl, mfma16(ah, bh, acc[m])));
        }
    }
}

// Laplacian aggregation on a C-fragment: D = L @ pre  (split bf16, 3 mfma, no lane moves)
__device__ __forceinline__ f32x4 agg3(bf8 Lhi, bf8 Llo, f32x4 p) {
    bf8 Bh = {0, 0, 0, 0, 0, 0, 0, 0};
    bf8 Bl = {0, 0, 0, 0, 0, 0, 0, 0};
#pragma unroll
    for (int q = 0; q < 4; ++q) {
        unsigned short h = f2bf(p[q]);
        Bh[q] = (short)h;
        Bl[q] = (short)f2bf(p[q] - bf2f(h));
    }
    f32x4 d = {0.f, 0.f, 0.f, 0.f};
    d = mfma16(Lhi, Bh, d);
    d = mfma16(Lhi, Bl, d);
    d = mfma16(Llo, Bh, d);
    return d;
}

__device__ __forceinline__ float plane_rd(const char* sm, unsigned hiOff, unsigned loOff,
                                          unsigned RS, unsigned row, unsigned col) {
    unsigned off = row * RS + ((col * 2u) ^ ((row & 7u) << 4));
    return bf2f(*(const unsigned short*)(sm + hiOff + off)) +
           bf2f(*(const unsigned short*)(sm + loOff + off));
}
__device__ __forceinline__ void plane_wr(char* sm, unsigned hiOff, unsigned loOff,
                                         unsigned RS, unsigned row, unsigned col, float v) {
    unsigned off = row * RS + ((col * 2u) ^ ((row & 7u) << 4));
    unsigned short h = f2bf(v);
    *(unsigned short*)(sm + hiOff + off) = h;
    *(unsigned short*)(sm + loOff + off) = f2bf(v - bf2f(h));
}

__device__ __forceinline__ float fast_sigm(float x) { return 1.0f / (1.0f + __expf(-x)); }
__device__ __forceinline__ float fast_tanh(float x) {
    x = fminf(fmaxf(x, -15.f), 15.f);
    float e = __expf(2.0f * x);
    return (e - 1.0f) / (e + 1.0f);
}

// stage x(t) -> X hi/lo planes (swizzled). Executed by threads 0..511.
__device__ __forceinline__ void stageX(char* sm, const float* __restrict__ feat,
                                       int b0, int t, int tid) {
    f32x4 v[8];
#pragma unroll
    for (int p = 0; p < 8; ++p) {
        int e = tid + p * 512;
        int row = e >> 6, c4 = (e & 63) << 2;
        size_t gi = (((size_t)(b0 + (row >> 4)) * 5 + t) * 16 + (row & 15)) * 256 + c4;
        v[p] = __builtin_nontemporal_load((const f32x4*)(feat + gi));
    }
#pragma unroll
    for (int p = 0; p < 8; ++p) {
        int e = tid + p * 512;
        int row = e >> 6, c4 = (e & 63) << 2;
        unsigned off = (unsigned)row * 512u + (((unsigned)c4 * 2u) ^ (((unsigned)row & 7u) << 4));
        us4 hi, lo;
#pragma unroll
        for (int q = 0; q < 4; ++q) {
            unsigned short h = f2bf(v[p][q]);
            hi[q] = h;
            lo[q] = f2bf(v[p][q] - bf2f(h));
        }
        *(us4*)(sm + XHI + off) = hi;
        *(us4*)(sm + XLO + off) = lo;
    }
}

// ---------------- prep: Laplacian fragments ----------------
__global__ void tgcn_prep_L(const float* __restrict__ adj, char* __restrict__ ws) {
    __shared__ float d[16];
    __shared__ float Lm[16][16];
    int tid = threadIdx.x;
    if (tid < 16) {
        float rs = 1.0f;
        for (int j = 0; j < 16; ++j) rs += adj[tid * 16 + j];
        d[tid] = 1.0f / sqrtf(rs);
    }
    __syncthreads();
    if (tid < 256) {
        int i = tid >> 4, j = tid & 15;
        Lm[i][j] = (adj[j * 16 + i] + (i == j ? 1.0f : 0.0f)) * d[i] * d[j];
    }
    __syncthreads();
    if (tid < 128) {
        int h = tid >> 6, ll = tid & 63;
        int a = ll & 15, g = ll >> 4;
        bf8 f = {0, 0, 0, 0, 0, 0, 0, 0};
        // k-permutation: slot (lg, j<4) represents node 4*lg+j (consistent with agg3's B pack)
        for (int j = 0; j < 4; ++j) {
            float v = Lm[a][4 * g + j];
            unsigned short hi = f2bf(v);
            f[j] = (short)(h == 0 ? hi : f2bf(v - bf2f(hi)));
        }
        *(bf8*)(ws + WS_LFRAG + h * 1024 + ll * 16) = f;
    }
}

// ---------------- prep: weight fragment packing (hi/lo bf16) ----------------
__global__ void tgcn_prep_W(const float* __restrict__ w1g, const float* __restrict__ w1c,
                            const float* __restrict__ w2g, const float* __restrict__ w2c,
                            char* __restrict__ ws) {
    int gid = blockIdx.x * 256 + threadIdx.x;  // 480 frags * 64 lanes = 30720
    if (gid >= 30720) return;
    int fid = gid >> 6, l = gid & 63;
    const float* src; char* dst; int NK, N, nt, ks;
    if (fid < 192)      { src = w1g; dst = ws + WS_W1G; NK = 12; N = 256; nt = fid / 12; ks = fid % 12; }
    else if (fid < 288) { int f = fid - 192; src = w1c; dst = ws + WS_W1C; NK = 12; N = 128; nt = f / 12; ks = f % 12; }
    else if (fid < 416) { int f = fid - 288; src = w2g; dst = ws + WS_W2G; NK = 8;  N = 256; nt = f / 8;  ks = f % 8; }
    else                { int f = fid - 416; src = w2c; dst = ws + WS_W2C; NK = 8;  N = 128; nt = f / 8;  ks = f % 8; }
    int col = nt * 16 + (l & 15);
    int kbase = ks * 32 + (l >> 4) * 8;
    bf8 hi, lo;
#pragma unroll
    for (int j = 0; j < 8; ++j) {
        float v = src[(size_t)(kbase + j) * N + col];
        unsigned short h = f2bf(v);
        hi[j] = (short)h;
        lo[j] = (short)f2bf(v - bf2f(h));
    }
    char* base = dst + ((size_t)(nt * NK + ks) * 2048) + l * 16;
    *(bf8*)(base) = hi;
    *(bf8*)(base + 1024) = lo;
}

// ---------------- main fused kernel ----------------
// 1024 threads (16 waves), 64 rows (4 batches), 160 KB LDS -> 1 block/CU = 4 waves/SIMD.
// This REQUIRES <=128 VGPRs; waves_per_eu(4,4) pins the allocator to that budget.
// Wave w owns gate n-tile nt=w (single B-load per fragment per block).
// Waves 8..15 (u-tile owners) run the cand GEMMs alone (u stays in registers);
// waves 0..7 use the cand2 window to stage x(t+1).
__global__ __launch_bounds__(NTHR)
__attribute__((amdgpu_waves_per_eu(4, 4)))
void tgcn_main(
    const float* __restrict__ feat, const char* __restrict__ ws,
    const float* __restrict__ b1g, const float* __restrict__ b2g,
    const float* __restrict__ bng, const float* __restrict__ bnb,
    const float* __restrict__ bnm, const float* __restrict__ bnv,
    const float* __restrict__ fcw, const float* __restrict__ fcb,
    float* __restrict__ out) {
    extern __shared__ char sm[];
    const int tid = threadIdx.x;
    const int b0 = blockIdx.x * 4;
    const unsigned l = (unsigned)tid & 63u, w = (unsigned)tid >> 6;  // wave 0..15
    const unsigned lrow = l & 15u, lg = l >> 4;
    const bool hiW = (w >= 8u);          // cand-owning waves
    const unsigned ntc = hiW ? (w - 8u) : 0u;  // cand n-tile

    const bf8 Lhi = *(const bf8*)(ws + WS_LFRAG + l * 16u);
    const bf8 Llo = *(const bf8*)(ws + WS_LFRAG + 1024u + l * 16u);

    const float bias1 = b1g[w * 16u + lrow];
    const float bias2 = b2g[w * 16u + lrow];

    // zero h1 + h2 plane regions (65536 B starting at H1HI)
    {
        const f32x4 z = {0.f, 0.f, 0.f, 0.f};
#pragma unroll
        for (int p = 0; p < 4; ++p)
            *(f32x4*)(sm + H1HI + (unsigned)(tid + p * NTHR) * 16u) = z;
    }
    if (tid < 512) stageX(sm, feat, b0, 0, tid);
    __syncthreads();  // b1

    const char* wsW1G = ws + WS_W1G;
    const char* wsW1C = ws + WS_W1C;
    const char* wsW2G = ws + WS_W2G;
    const char* wsW2C = ws + WS_W2C;
    const f32x4 zf = {0.f, 0.f, 0.f, 0.f};

    float u1[4][4];  // u-gate values (waves 8..15), frag layout [m][q]

    for (int t = 0; t < 5; ++t) {
        // ---- gates1: [x | h1] @ w1g, K=384. Wave w -> nt=w, 4 M-tiles.
        {
            f32x4 acc[4] = {zf, zf, zf, zf};
            const char* wp = wsW1G + ((size_t)(w * 12u) * 2048u) + l * 16u;
            gemmSeg<8>(sm, XHI, XLO, 512u, wp, l, acc);
            gemmSeg<4>(sm, H1HI, H1LO, 256u, wp + (size_t)8 * 2048u, l, acc);
            const unsigned col = w * 16u + lrow;
#pragma unroll
            for (int m = 0; m < 4; ++m) {
                f32x4 g = agg3(Lhi, Llo, acc[m]);
                if (!hiW) {  // r tile -> rh = r*h1 into G planes (col 0..127)
#pragma unroll
                    for (int q = 0; q < 4; ++q) {
                        float s = fast_sigm(g[q] + bias1);
                        unsigned row = (unsigned)m * 16u + lg * 4u + (unsigned)q;
                        float h1v = plane_rd(sm, H1HI, H1LO, 256u, row, col);
                        plane_wr(sm, GHI, GLO, 256u, row, col, s * h1v);
                    }
                } else {     // u tile -> registers
#pragma unroll
                    for (int q = 0; q < 4; ++q) u1[m][q] = fast_sigm(g[q] + bias1);
                }
            }
        }
        __syncthreads();  // b2: G(rh) ready

        // ---- cand1: [x | rh] @ w1c, K=384. Waves 8..15 only; h1 update in place.
        if (hiW) {
            f32x4 acc[4] = {zf, zf, zf, zf};
            const char* wp = wsW1C + ((size_t)(ntc * 12u) * 2048u) + l * 16u;
            gemmSeg<8>(sm, XHI, XLO, 512u, wp, l, acc);
            gemmSeg<4>(sm, GHI, GLO, 256u, wp + (size_t)8 * 2048u, l, acc);
            const unsigned col = ntc * 16u + lrow;
#pragma unroll
            for (int m = 0; m < 4; ++m) {
                f32x4 c = agg3(Lhi, Llo, acc[m]);
#pragma unroll
                for (int q = 0; q < 4; ++q) {
                    float cv = fast_tanh(c[q]);
                    float u = u1[m][q];
                    unsigned row = (unsigned)m * 16u + lg * 4u + (unsigned)q;
                    float hv = plane_rd(sm, H1HI, H1LO, 256u, row, col);
                    plane_wr(sm, H1HI, H1LO, 256u, row, col, u * hv + (1.0f - u) * cv);
                }
            }
        }
        __syncthreads();  // b3: h1 updated

        // ---- gates2: [h1 | h2] @ w2g, K=256. All waves, nt=w.
        {
            f32x4 acc[4] = {zf, zf, zf, zf};
            const char* wp = wsW2G + ((size_t)(w * 8u) * 2048u) + l * 16u;
            gemmSeg<4>(sm, H1HI, H1LO, 256u, wp, l, acc);
            gemmSeg<4>(sm, SHI, SLO, 256u, wp + (size_t)4 * 2048u, l, acc);
            const unsigned col = w * 16u + lrow;
#pragma unroll
            for (int m = 0; m < 4; ++m) {
                f32x4 g = agg3(Lhi, Llo, acc[m]);
                if (!hiW) {  // rh2 = r2*h2 into G planes
#pragma unroll
                    for (int q = 0; q < 4; ++q) {
                        float s = fast_sigm(g[q] + bias2);
                        unsigned row = (unsigned)m * 16u + lg * 4u + (unsigned)q;
                        float h2v = plane_rd(sm, SHI, SLO, 256u, row, col);
                        plane_wr(sm, GHI, GLO, 256u, row, col, s * h2v);
                    }
                } else {
#pragma unroll
                    for (int q = 0; q < 4; ++q) u1[m][q] = fast_sigm(g[q] + bias2);
                }
            }
        }
        __syncthreads();  // b4: G(rh2) ready

        // ---- cand2 (waves 8..15): [h1 | rh2] @ w2c, K=256; h2 update.
        //      Meanwhile waves 0..7 stage x(t+1) into the (now free) X planes.
        if (hiW) {
            f32x4 acc[4] = {zf, zf, zf, zf};
            const char* wp = wsW2C + ((size_t)(ntc * 8u) * 2048u) + l * 16u;
            gemmSeg<4>(sm, H1HI, H1LO, 256u, wp, l, acc);
            gemmSeg<4>(sm, GHI, GLO, 256u, wp + (size_t)4 * 2048u, l, acc);
            const unsigned col = ntc * 16u + lrow;
#pragma unroll
            for (int m = 0; m < 4; ++m) {
                f32x4 c = agg3(Lhi, Llo, acc[m]);
#pragma unroll
                for (int q = 0; q < 4; ++q) {
                    float cv = fast_tanh(c[q]);
                    float u = u1[m][q];
                    unsigned row = (unsigned)m * 16u + lg * 4u + (unsigned)q;
                    float hv = plane_rd(sm, SHI, SLO, 256u, row, col);
                    plane_wr(sm, SHI, SLO, 256u, row, col, u * hv + (1.0f - u) * cv);
                }
            }
        } else if (t < 4) {
            stageX(sm, feat, b0, t + 1, tid);
        }
        __syncthreads();  // b5: h2 updated, x(t+1) staged
    }

    // ---- head: BN -> ReLU -> FC(2048->2) from h2 (S planes)
    {
        int row = tid >> 4, cb = tid & 15;   // 64 rows x 16 col-blocks of 8
        int a = row & 15;
        unsigned sw = ((unsigned)row & 7u) << 4;
        unsigned o0 = (unsigned)row * 256u + (((unsigned)cb * 16u) ^ sw);
        bf8 hA = *(const bf8*)(sm + SHI + o0);
        bf8 lA = *(const bf8*)(sm + SLO + o0);
        int k2 = a * 128 + cb * 8;
        float p0 = 0.f, p1 = 0.f;
#pragma unroll
        for (int j = 0; j < 8; ++j) {
            float v = bf2f((unsigned short)hA[j]) + bf2f((unsigned short)lA[j]);
            int k = k2 + j;
            float x = bng[k] * (v - bnm[k]) * rsqrtf(bnv[k] + 1e-5f) + bnb[k];
            x = fmaxf(x, 0.f);
            p0 += x * fcw[2 * k];
            p1 += x * fcw[2 * k + 1];
        }
        p0 += __shfl_down(p0, 8, 16); p0 += __shfl_down(p0, 4, 16);
        p0 += __shfl_down(p0, 2, 16); p0 += __shfl_down(p0, 1, 16);
        p1 += __shfl_down(p1, 8, 16); p1 += __shfl_down(p1, 4, 16);
        p1 += __shfl_down(p1, 2, 16); p1 += __shfl_down(p1, 1, 16);
        if (cb == 0) {
            ((float*)(sm + GHI))[row * 2] = p0;
            ((float*)(sm + GHI))[row * 2 + 1] = p1;
        }
        __syncthreads();
        if (tid < 8) {
            int b = tid >> 1, o = tid & 1;
            float s = fcb[o];
#pragma unroll
            for (int aa = 0; aa < 16; ++aa) s += ((const float*)(sm + GHI))[(b * 16 + aa) * 2 + o];
            out[(size_t)(b0 + b) * 2 + o] = s;
        }
    }
}

extern "C" void kernel_launch(void* const* d_in, const int* in_sizes, int n_in,
                              void* d_out, int out_size, void* d_ws, size_t ws_size,
                              hipStream_t stream) {
    const float* feat = (const float*)d_in[0];
    const float* adj  = (const float*)d_in[1];
    const float* w1g  = (const float*)d_in[2];
    const float* b1g  = (const float*)d_in[3];
    const float* w1c  = (const float*)d_in[4];
    const float* w2g  = (const float*)d_in[5];
    const float* b2g  = (const float*)d_in[6];
    const float* w2c  = (const float*)d_in[7];
    const float* bng  = (const float*)d_in[8];
    const float* bnb  = (const float*)d_in[9];
    const float* bnm  = (const float*)d_in[10];
    const float* bnv  = (const float*)d_in[11];
    const float* fcw  = (const float*)d_in[12];
    const float* fcb  = (const float*)d_in[13];
    float* out = (float*)d_out;
    char* ws = (char*)d_ws;

    int B = in_sizes[0] / (5 * 16 * 256);  // 4096

    hipFuncSetAttribute((const void*)tgcn_main,
                        hipFuncAttributeMaxDynamicSharedMemorySize, LDS_TOTAL);

    tgcn_prep_L<<<1, 256, 0, stream>>>(adj, ws);
    tgcn_prep_W<<<120, 256, 0, stream>>>(w1g, w1c, w2g, w2c, ws);
    tgcn_main<<<B / 4, NTHR, LDS_TOTAL, stream>>>(feat, ws, b1g, b2g,
                                                  bng, bnb, bnm, bnv, fcw, fcb, out);
}

// Round 6
// 646.058 us; speedup vs baseline: 1.1867x; 1.1867x over previous
//
#include <hip/hip_runtime.h>
#include <math.h>

typedef __attribute__((ext_vector_type(8))) short bf8;
typedef __attribute__((ext_vector_type(4))) float f32x4;
typedef __attribute__((ext_vector_type(4))) unsigned short us4;

#define NTHR 512

// ---- LDS layout (bytes). All "planes" are bf16, XOR-swizzled byte^=((row&7)<<4).
#define XHI 0u          // x hi   [64][256] bf16, row stride 512B
#define XLO 32768u      // x lo
#define GHI 65536u      // rh / scratch hi [64][128], row stride 256B
#define GLO 81920u
#define H1HI 98304u     // h1 hi [64][128]
#define H1LO 114688u
#define SHI 131072u     // h2 hi [64][128]
#define SLO 147456u
#define LDS_TOTAL 163840

// ---- workspace layout (bytes)
#define WS_LFRAG 0                      // 2 x 1KB L fragments (hi, lo)
#define WS_W1G   4096                   // 16nt*12ks*2*1024 = 393216
#define WS_W1C   (WS_W1G + 393216)      // 8nt*12ks*2*1024 = 196608
#define WS_W2G   (WS_W1C + 196608)      // 16nt*8ks*2*1024 = 262144
#define WS_W2C   (WS_W2G + 262144)      // 8nt*8ks*2*1024 = 131072

__device__ __forceinline__ unsigned short f2bf(float x) {
    unsigned u = __float_as_uint(x);
    unsigned r = (u + 0x7fffu + ((u >> 16) & 1u)) >> 16;
    return (unsigned short)r;
}
__device__ __forceinline__ float bf2f(unsigned short h) {
    return __uint_as_float(((unsigned)h) << 16);
}
__device__ __forceinline__ f32x4 mfma16(bf8 a, bf8 b, f32x4 c) {
    return __builtin_amdgcn_mfma_f32_16x16x32_bf16(a, b, c, 0, 0, 0);
}

// GEMM segment, 4 M-tiles x 2 exclusive n-tiles. Each weight fragment is read by
// exactly ONE wave in the block (wp0/wp1 are this wave's n-tiles).
template<int KS>
__device__ __forceinline__ void gemm2nt(const char* sm, unsigned hiO, unsigned loO, unsigned rs,
                                        const char* wp0, const char* wp1,
                                        unsigned l, f32x4 (&acc)[4][2]) {
    const unsigned lrow = l & 15u, lk = l >> 4;
    const unsigned sw = (lrow & 7u) << 4;
#pragma unroll 2
    for (int ks = 0; ks < KS; ++ks) {
        const unsigned kb = ((unsigned)ks * 64u + lk * 16u) ^ sw;
        const bf8 bh0 = *(const bf8*)(wp0 + (size_t)ks * 2048u);
        const bf8 bl0 = *(const bf8*)(wp0 + (size_t)ks * 2048u + 1024u);
        const bf8 bh1 = *(const bf8*)(wp1 + (size_t)ks * 2048u);
        const bf8 bl1 = *(const bf8*)(wp1 + (size_t)ks * 2048u + 1024u);
#pragma unroll
        for (int m = 0; m < 4; ++m) {
            const unsigned ro = ((unsigned)m * 16u + lrow) * rs + kb;
            const bf8 ah = *(const bf8*)(sm + hiO + ro);
            const bf8 al = *(const bf8*)(sm + loO + ro);
            acc[m][0] = mfma16(al, bh0, mfma16(ah, bl0, mfma16(ah, bh0, acc[m][0])));
            acc[m][1] = mfma16(al, bh1, mfma16(ah, bl1, mfma16(ah, bh1, acc[m][1])));
        }
    }
}

// GEMM segment, 4 M-tiles x 1 n-tile (cand passes).
template<int KS>
__device__ __forceinline__ void gemm1nt(const char* sm, unsigned hiO, unsigned loO, unsigned rs,
                                        const char* wp, unsigned l, f32x4 (&acc)[4]) {
    const unsigned lrow = l & 15u, lk = l >> 4;
    const unsigned sw = (lrow & 7u) << 4;
#pragma unroll 2
    for (int ks = 0; ks < KS; ++ks) {
        const unsigned kb = ((unsigned)ks * 64u + lk * 16u) ^ sw;
        const bf8 bh = *(const bf8*)(wp + (size_t)ks * 2048u);
        const bf8 bl = *(const bf8*)(wp + (size_t)ks * 2048u + 1024u);
#pragma unroll
        for (int m = 0; m < 4; ++m) {
            const unsigned ro = ((unsigned)m * 16u + lrow) * rs + kb;
            const bf8 ah = *(const bf8*)(sm + hiO + ro);
            const bf8 al = *(const bf8*)(sm + loO + ro);
            acc[m] = mfma16(al, bh, mfma16(ah, bl, mfma16(ah, bh, acc[m])));
        }
    }
}

// Laplacian aggregation on a C-fragment: D = L @ pre  (split bf16, 3 mfma, no lane moves)
__device__ __forceinline__ f32x4 agg3(bf8 Lhi, bf8 Llo, f32x4 p) {
    bf8 Bh = {0, 0, 0, 0, 0, 0, 0, 0};
    bf8 Bl = {0, 0, 0, 0, 0, 0, 0, 0};
#pragma unroll
    for (int q = 0; q < 4; ++q) {
        unsigned short h = f2bf(p[q]);
        Bh[q] = (short)h;
        Bl[q] = (short)f2bf(p[q] - bf2f(h));
    }
    f32x4 d = {0.f, 0.f, 0.f, 0.f};
    d = mfma16(Lhi, Bh, d);
    d = mfma16(Lhi, Bl, d);
    d = mfma16(Llo, Bh, d);
    return d;
}

__device__ __forceinline__ float plane_rd(const char* sm, unsigned hiOff, unsigned loOff,
                                          unsigned RS, unsigned row, unsigned col) {
    unsigned off = row * RS + ((col * 2u) ^ ((row & 7u) << 4));
    return bf2f(*(const unsigned short*)(sm + hiOff + off)) +
           bf2f(*(const unsigned short*)(sm + loOff + off));
}
__device__ __forceinline__ void plane_wr(char* sm, unsigned hiOff, unsigned loOff,
                                         unsigned RS, unsigned row, unsigned col, float v) {
    unsigned off = row * RS + ((col * 2u) ^ ((row & 7u) << 4));
    unsigned short h = f2bf(v);
    *(unsigned short*)(sm + hiOff + off) = h;
    *(unsigned short*)(sm + loOff + off) = f2bf(v - bf2f(h));
}

__device__ __forceinline__ float fast_sigm(float x) { return 1.0f / (1.0f + __expf(-x)); }
__device__ __forceinline__ float fast_tanh(float x) {
    x = fminf(fmaxf(x, -15.f), 15.f);
    float e = __expf(2.0f * x);
    return (e - 1.0f) / (e + 1.0f);
}

// feature loads for tile t (registers only; no LDS traffic)
__device__ __forceinline__ void stage_load(f32x4 (&v)[8], const float* __restrict__ feat,
                                           int b0, int t, int tid) {
#pragma unroll
    for (int p = 0; p < 8; ++p) {
        int e = tid + p * NTHR;
        int row = e >> 6, c4 = (e & 63) << 2;
        size_t gi = (((size_t)(b0 + (row >> 4)) * 5 + t) * 16 + (row & 15)) * 256 + c4;
        v[p] = __builtin_nontemporal_load((const f32x4*)(feat + gi));
    }
}
// split to hi/lo bf16 planes (swizzled)
__device__ __forceinline__ void stage_store(char* sm, const f32x4 (&v)[8], int tid) {
#pragma unroll
    for (int p = 0; p < 8; ++p) {
        int e = tid + p * NTHR;
        int row = e >> 6, c4 = (e & 63) << 2;
        unsigned off = (unsigned)row * 512u + (((unsigned)c4 * 2u) ^ (((unsigned)row & 7u) << 4));
        us4 hi, lo;
#pragma unroll
        for (int q = 0; q < 4; ++q) {
            unsigned short h = f2bf(v[p][q]);
            hi[q] = h;
            lo[q] = f2bf(v[p][q] - bf2f(h));
        }
        *(us4*)(sm + XHI + off) = hi;
        *(us4*)(sm + XLO + off) = lo;
    }
}

// ---------------- prep: Laplacian fragments ----------------
__global__ void tgcn_prep_L(const float* __restrict__ adj, char* __restrict__ ws) {
    __shared__ float d[16];
    __shared__ float Lm[16][16];
    int tid = threadIdx.x;
    if (tid < 16) {
        float rs = 1.0f;
        for (int j = 0; j < 16; ++j) rs += adj[tid * 16 + j];
        d[tid] = 1.0f / sqrtf(rs);
    }
    __syncthreads();
    if (tid < 256) {
        int i = tid >> 4, j = tid & 15;
        Lm[i][j] = (adj[j * 16 + i] + (i == j ? 1.0f : 0.0f)) * d[i] * d[j];
    }
    __syncthreads();
    if (tid < 128) {
        int h = tid >> 6, ll = tid & 63;
        int a = ll & 15, g = ll >> 4;
        bf8 f = {0, 0, 0, 0, 0, 0, 0, 0};
        // k-permutation: slot (lg, j<4) represents node 4*lg+j (consistent with agg3's B pack)
        for (int j = 0; j < 4; ++j) {
            float v = Lm[a][4 * g + j];
            unsigned short hi = f2bf(v);
            f[j] = (short)(h == 0 ? hi : f2bf(v - bf2f(hi)));
        }
        *(bf8*)(ws + WS_LFRAG + h * 1024 + ll * 16) = f;
    }
}

// ---------------- prep: weight fragment packing (hi/lo bf16) ----------------
__global__ void tgcn_prep_W(const float* __restrict__ w1g, const float* __restrict__ w1c,
                            const float* __restrict__ w2g, const float* __restrict__ w2c,
                            char* __restrict__ ws) {
    int gid = blockIdx.x * 256 + threadIdx.x;  // 480 frags * 64 lanes = 30720
    if (gid >= 30720) return;
    int fid = gid >> 6, l = gid & 63;
    const float* src; char* dst; int NK, N, nt, ks;
    if (fid < 192)      { src = w1g; dst = ws + WS_W1G; NK = 12; N = 256; nt = fid / 12; ks = fid % 12; }
    else if (fid < 288) { int f = fid - 192; src = w1c; dst = ws + WS_W1C; NK = 12; N = 128; nt = f / 12; ks = f % 12; }
    else if (fid < 416) { int f = fid - 288; src = w2g; dst = ws + WS_W2G; NK = 8;  N = 256; nt = f / 8;  ks = f % 8; }
    else                { int f = fid - 416; src = w2c; dst = ws + WS_W2C; NK = 8;  N = 128; nt = f / 8;  ks = f % 8; }
    int col = nt * 16 + (l & 15);
    int kbase = ks * 32 + (l >> 4) * 8;
    bf8 hi, lo;
#pragma unroll
    for (int j = 0; j < 8; ++j) {
        float v = src[(size_t)(kbase + j) * N + col];
        unsigned short h = f2bf(v);
        hi[j] = (short)h;
        lo[j] = (short)f2bf(v - bf2f(h));
    }
    char* base = dst + ((size_t)(nt * NK + ks) * 2048) + l * 16;
    *(bf8*)(base) = hi;
    *(bf8*)(base + 1024) = lo;
}

// ---------------- main fused kernel ----------------
// 512 threads (8 waves), 64 rows (4 batches), 160 KB LDS -> 1 block/CU, 2 waves/SIMD.
// waves_per_eu(2,2) -> 256-VGPR budget (R4 proved this point spill-free).
// Wave w owns gate n-tiles {w (r-gate), w+8 (u-gate)} and cand n-tile w:
// every weight fragment is loaded by exactly one wave -> minimal L2 traffic,
// and the u-gate lives in the registers of the wave that applies it.
__global__ __launch_bounds__(NTHR)
__attribute__((amdgpu_waves_per_eu(2, 2)))
void tgcn_main(
    const float* __restrict__ feat, const char* __restrict__ ws,
    const float* __restrict__ b1g, const float* __restrict__ b2g,
    const float* __restrict__ bng, const float* __restrict__ bnb,
    const float* __restrict__ bnm, const float* __restrict__ bnv,
    const float* __restrict__ fcw, const float* __restrict__ fcb,
    float* __restrict__ out) {
    extern __shared__ char sm[];
    const int tid = threadIdx.x;
    const int b0 = blockIdx.x * 4;
    const unsigned l = (unsigned)tid & 63u, w = (unsigned)tid >> 6;  // wave 0..7
    const unsigned lrow = l & 15u, lg = l >> 4;

    const bf8 Lhi = *(const bf8*)(ws + WS_LFRAG + l * 16u);
    const bf8 Llo = *(const bf8*)(ws + WS_LFRAG + 1024u + l * 16u);

    const float b1r = b1g[w * 16u + lrow];
    const float b1u = b1g[128u + w * 16u + lrow];
    const float b2r = b2g[w * 16u + lrow];
    const float b2u = b2g[128u + w * 16u + lrow];
    const unsigned col = w * 16u + lrow;   // this wave's H-column

    // zero h1 + h2 plane regions (65536 B starting at H1HI)
    {
        const f32x4 z = {0.f, 0.f, 0.f, 0.f};
#pragma unroll
        for (int p = 0; p < 8; ++p)
            *(f32x4*)(sm + H1HI + (unsigned)(tid + p * NTHR) * 16u) = z;
    }
    {
        f32x4 v[8];
        stage_load(v, feat, b0, 0, tid);
        stage_store(sm, v, tid);
    }
    __syncthreads();  // b1: X(0), h=0 ready

    const char* wsW1G = ws + WS_W1G;
    const char* wsW1C = ws + WS_W1C;
    const char* wsW2G = ws + WS_W2G;
    const char* wsW2C = ws + WS_W2C;
    const f32x4 zf = {0.f, 0.f, 0.f, 0.f};

    float u1[4][4];  // this wave's u-gate fragment [m][q]

    for (int t = 0; t < 5; ++t) {
        // prefetch x(t+1) into registers; written to X planes after cand1 (b3)
        f32x4 vx[8];
        if (t < 4) stage_load(vx, feat, b0, t + 1, tid);

        // ---- gates1: [x | h1] @ w1g, K=384. nt = {w, w+8}.
        {
            f32x4 acc[4][2] = {{zf, zf}, {zf, zf}, {zf, zf}, {zf, zf}};
            const char* wp0 = wsW1G + ((size_t)(w * 12u) * 2048u) + l * 16u;
            const char* wp1 = wsW1G + ((size_t)((w + 8u) * 12u) * 2048u) + l * 16u;
            gemm2nt<8>(sm, XHI, XLO, 512u, wp0, wp1, l, acc);
            gemm2nt<4>(sm, H1HI, H1LO, 256u, wp0 + (size_t)8 * 2048u, wp1 + (size_t)8 * 2048u, l, acc);
#pragma unroll
            for (int m = 0; m < 4; ++m) {
                f32x4 gr = agg3(Lhi, Llo, acc[m][0]);
                f32x4 gu = agg3(Lhi, Llo, acc[m][1]);
#pragma unroll
                for (int q = 0; q < 4; ++q) {
                    float s = fast_sigm(gr[q] + b1r);
                    unsigned row = (unsigned)m * 16u + lg * 4u + (unsigned)q;
                    float h1v = plane_rd(sm, H1HI, H1LO, 256u, row, col);
                    plane_wr(sm, GHI, GLO, 256u, row, col, s * h1v);
                    u1[m][q] = fast_sigm(gu[q] + b1u);
                }
            }
        }
        __syncthreads();  // b2: G(rh) ready

        // ---- cand1: [x | rh] @ w1c, K=384. nt = w; h1 update in place.
        {
            f32x4 acc[4] = {zf, zf, zf, zf};
            const char* wp = wsW1C + ((size_t)(w * 12u) * 2048u) + l * 16u;
            gemm1nt<8>(sm, XHI, XLO, 512u, wp, l, acc);
            gemm1nt<4>(sm, GHI, GLO, 256u, wp + (size_t)8 * 2048u, l, acc);
#pragma unroll
            for (int m = 0; m < 4; ++m) {
                f32x4 c = agg3(Lhi, Llo, acc[m]);
#pragma unroll
                for (int q = 0; q < 4; ++q) {
                    float cv = fast_tanh(c[q]);
                    float u = u1[m][q];
                    unsigned row = (unsigned)m * 16u + lg * 4u + (unsigned)q;
                    float hv = plane_rd(sm, H1HI, H1LO, 256u, row, col);
                    plane_wr(sm, H1HI, H1LO, 256u, row, col, u * hv + (1.0f - u) * cv);
                }
            }
        }
        __syncthreads();  // b3: h1 updated, X free

        // stage x(t+1) into X planes (X unused until next-t gates1; barriers b4/b5 order it)
        if (t < 4) stage_store(sm, vx, tid);

        // ---- gates2: [h1 | h2] @ w2g, K=256. nt = {w, w+8}.
        {
            f32x4 acc[4][2] = {{zf, zf}, {zf, zf}, {zf, zf}, {zf, zf}};
            const char* wp0 = wsW2G + ((size_t)(w * 8u) * 2048u) + l * 16u;
            const char* wp1 = wsW2G + ((size_t)((w + 8u) * 8u) * 2048u) + l * 16u;
            gemm2nt<4>(sm, H1HI, H1LO, 256u, wp0, wp1, l, acc);
            gemm2nt<4>(sm, SHI, SLO, 256u, wp0 + (size_t)4 * 2048u, wp1 + (size_t)4 * 2048u, l, acc);
#pragma unroll
            for (int m = 0; m < 4; ++m) {
                f32x4 gr = agg3(Lhi, Llo, acc[m][0]);
                f32x4 gu = agg3(Lhi, Llo, acc[m][1]);
#pragma unroll
                for (int q = 0; q < 4; ++q) {
                    float s = fast_sigm(gr[q] + b2r);
                    unsigned row = (unsigned)m * 16u + lg * 4u + (unsigned)q;
                    float h2v = plane_rd(sm, SHI, SLO, 256u, row, col);
                    plane_wr(sm, GHI, GLO, 256u, row, col, s * h2v);
                    u1[m][q] = fast_sigm(gu[q] + b2u);
                }
            }
        }
        __syncthreads();  // b4: G(rh2) ready

        // ---- cand2: [h1 | rh2] @ w2c, K=256. nt = w; h2 update.
        {
            f32x4 acc[4] = {zf, zf, zf, zf};
            const char* wp = wsW2C + ((size_t)(w * 8u) * 2048u) + l * 16u;
            gemm1nt<4>(sm, H1HI, H1LO, 256u, wp, l, acc);
            gemm1nt<4>(sm, GHI, GLO, 256u, wp + (size_t)4 * 2048u, l, acc);
#pragma unroll
            for (int m = 0; m < 4; ++m) {
                f32x4 c = agg3(Lhi, Llo, acc[m]);
#pragma unroll
                for (int q = 0; q < 4; ++q) {
                    float cv = fast_tanh(c[q]);
                    float u = u1[m][q];
                    unsigned row = (unsigned)m * 16u + lg * 4u + (unsigned)q;
                    float hv = plane_rd(sm, SHI, SLO, 256u, row, col);
                    plane_wr(sm, SHI, SLO, 256u, row, col, u * hv + (1.0f - u) * cv);
                }
            }
        }
        __syncthreads();  // b5: h2 updated, X(t+1) staged
    }

    // ---- head: BN -> ReLU -> FC(2048->2) from h2 (S planes)
    {
        int row = tid >> 3, cb = tid & 7;
        int a = row & 15;
        unsigned c0 = (unsigned)cb * 16u;
        unsigned sw = ((unsigned)row & 7u) << 4;
        unsigned base = (unsigned)row * 256u;
        unsigned o0 = base + ((c0 * 2u) ^ sw);
        unsigned o1 = base + ((c0 * 2u + 16u) ^ sw);
        bf8 hA = *(const bf8*)(sm + SHI + o0);
        bf8 hB = *(const bf8*)(sm + SHI + o1);
        bf8 lA = *(const bf8*)(sm + SLO + o0);
        bf8 lB = *(const bf8*)(sm + SLO + o1);
        int k2 = a * 128 + (int)c0;
        float p0 = 0.f, p1 = 0.f;
#pragma unroll
        for (int j = 0; j < 16; ++j) {
            unsigned short hh = (unsigned short)(j < 8 ? hA[j] : hB[j - 8]);
            unsigned short ll = (unsigned short)(j < 8 ? lA[j] : lB[j - 8]);
            float v = bf2f(hh) + bf2f(ll);
            int k = k2 + j;
            float x = bng[k] * (v - bnm[k]) * rsqrtf(bnv[k] + 1e-5f) + bnb[k];
            x = fmaxf(x, 0.f);
            p0 += x * fcw[2 * k];
            p1 += x * fcw[2 * k + 1];
        }
        p0 += __shfl_down(p0, 4, 8); p0 += __shfl_down(p0, 2, 8); p0 += __shfl_down(p0, 1, 8);
        p1 += __shfl_down(p1, 4, 8); p1 += __shfl_down(p1, 2, 8); p1 += __shfl_down(p1, 1, 8);
        if ((tid & 7) == 0) {
            ((float*)(sm + GHI))[row * 2] = p0;
            ((float*)(sm + GHI))[row * 2 + 1] = p1;
        }
        __syncthreads();
        if (tid < 8) {
            int b = tid >> 1, o = tid & 1;
            float s = fcb[o];
#pragma unroll
            for (int aa = 0; aa < 16; ++aa) s += ((const float*)(sm + GHI))[(b * 16 + aa) * 2 + o];
            out[(size_t)(b0 + b) * 2 + o] = s;
        }
    }
}

extern "C" void kernel_launch(void* const* d_in, const int* in_sizes, int n_in,
                              void* d_out, int out_size, void* d_ws, size_t ws_size,
                              hipStream_t stream) {
    const float* feat = (const float*)d_in[0];
    const float* adj  = (const float*)d_in[1];
    const float* w1g  = (const float*)d_in[2];
    const float* b1g  = (const float*)d_in[3];
    const float* w1c  = (const float*)d_in[4];
    const float* w2g  = (const float*)d_in[5];
    const float* b2g  = (const float*)d_in[6];
    const float* w2c  = (const float*)d_in[7];
    const float* bng  = (const float*)d_in[8];
    const float* bnb  = (const float*)d_in[9];
    const float* bnm  = (const float*)d_in[10];
    const float* bnv  = (const float*)d_in[11];
    const float* fcw  = (const float*)d_in[12];
    const float* fcb  = (const float*)d_in[13];
    float* out = (float*)d_out;
    char* ws = (char*)d_ws;

    int B = in_sizes[0] / (5 * 16 * 256);  // 4096

    hipFuncSetAttribute((const void*)tgcn_main,
                        hipFuncAttributeMaxDynamicSharedMemorySize, LDS_TOTAL);

    tgcn_prep_L<<<1, 256, 0, stream>>>(adj, ws);
    tgcn_prep_W<<<120, 256, 0, stream>>>(w1g, w1c, w2g, w2c, ws);
    tgcn_main<<<B / 4, NTHR, LDS_TOTAL, stream>>>(feat, ws, b1g, b2g,
                                                  bng, bnb, bnm, bnv, fcw, fcb, out);
}